// Round 9
// baseline (355.204 us; speedup 1.0000x reference)
//
#include <hip/hip_runtime.h>
#include <hip/hip_bf16.h>
#include <math.h>

// Problem constants
#define B_   8
#define H_   8
#define S_   2048
#define D_   64      // head dim
#define BH_  64      // B*H
#define DPROJ_ 512

typedef __attribute__((ext_vector_type(8)))  _Float16 f16x8;
typedef __attribute__((ext_vector_type(4)))  float    f32x4;
typedef __attribute__((ext_vector_type(16))) float    f32x16;
typedef __attribute__((ext_vector_type(4)))  int      i32x4;

static __device__ __forceinline__ short f16bits(float f) {
    return __builtin_bit_cast(short, (_Float16)f);   // v_cvt_f16_f32 (RNE)
}

static __device__ __forceinline__ f16x8 load8_f32_f16(const float* p) {
    const float4 a = ((const float4*)p)[0];
    const float4 b = ((const float4*)p)[1];
    f16x8 r;
    r[0] = (_Float16)a.x; r[1] = (_Float16)a.y; r[2] = (_Float16)a.z; r[3] = (_Float16)a.w;
    r[4] = (_Float16)b.x; r[5] = (_Float16)b.y; r[6] = (_Float16)b.z; r[7] = (_Float16)b.w;
    return r;
}

// ---------------------------------------------------------------------------
// Kernel 1a: Q/K projection (unchanged — passes, minor cost).
// ---------------------------------------------------------------------------
#define QKST 520

__global__ __launch_bounds__(256)
void proj_qk_kernel(const float* __restrict__ query, const float* __restrict__ key,
                    const float* __restrict__ Wq, const float* __restrict__ bq,
                    const float* __restrict__ Wk, const float* __restrict__ bk,
                    short* __restrict__ qws, short* __restrict__ kws)
{
    __shared__ __align__(16) short tile[16 * QKST];

    const int tid  = threadIdx.x;
    const int wave = tid >> 6;
    const int lane = tid & 63;
    const int n    = lane & 15;
    const int quad = lane >> 4;
    const int r0   = blockIdx.x * 16;
    const int kind = blockIdx.y;             // 0=q, 1=k
    const int b    = r0 >> 11;
    const int s0   = r0 & 2047;
    const float QS = 0.1125f;                // (1-dropout)/num_heads = 0.9/8

    const float* X    = kind ? key : query;
    const float* W    = kind ? Wk  : Wq;
    const float* bias = kind ? bk  : bq;
    short*       ows  = kind ? kws : qws;

    f16x8 af = load8_f32_f16(X + (r0 + n) * 32 + quad * 8);
    #pragma unroll
    for (int i = 0; i < 8; ++i) {
        const int c0 = wave * 128 + i * 16;
        f16x8 bfr = load8_f32_f16(W + (c0 + n) * 32 + quad * 8);
        f32x4 acc = {0.f, 0.f, 0.f, 0.f};
        acc = __builtin_amdgcn_mfma_f32_16x16x32_f16(af, bfr, acc, 0, 0, 0);
        const int c = c0 + n;
        const float bsf = bias[c];
        #pragma unroll
        for (int r = 0; r < 4; ++r) {
            float v = acc[r] + bsf;
            if (kind == 0) v *= QS;
            tile[(quad * 4 + r) * QKST + c] = f16bits(v);
        }
    }
    __syncthreads();

    #pragma unroll
    for (int k = 0; k < 4; ++k) {
        const int slot = k * 256 + tid;
        const int li   = slot & 7;
        const int chunk= slot >> 3;
        const int row  = chunk & 15;
        const int h    = chunk >> 4;
        uint4 vv = *(const uint4*)(tile + row * QKST + h * 64 + li * 8);
        *(uint4*)(ows + ((size_t)(b * 8 + h) * S_ + s0 + row) * 64 + li * 8) = vv;
    }
}

// ---------------------------------------------------------------------------
// Kernel 1b: V projection (unchanged). v_ws: [BH][64][S] f16.
// ---------------------------------------------------------------------------
__global__ __launch_bounds__(256)
void proj_v_kernel(const float* __restrict__ value,
                   const float* __restrict__ Wv, const float* __restrict__ bv,
                   short* __restrict__ vws)
{
    __shared__ __align__(16) short vtile[2 * 256 * 32];   // 32 KB

    const int tid  = threadIdx.x;
    const int wave = tid >> 6;
    const int lane = tid & 63;
    const int n    = lane & 15;
    const int quad = lane >> 4;
    const int r0   = blockIdx.x * 64;
    const int cb   = blockIdx.y * 256;
    const int b    = r0 >> 11;
    const int s0   = r0 & 2047;
    const int sub  = wave >> 1;
    const int sh   = (wave & 1) * 16;

    f16x8 bfr = load8_f32_f16(value + (r0 + sub * 32 + sh + n) * 32 + quad * 8);
    #pragma unroll
    for (int i = 0; i < 16; ++i) {
        const int c0 = cb + i * 16;
        f16x8 af = load8_f32_f16(Wv + (c0 + n) * 32 + quad * 8);
        f32x4 acc = {0.f, 0.f, 0.f, 0.f};
        acc = __builtin_amdgcn_mfma_f32_16x16x32_f16(af, bfr, acc, 0, 0, 0);
        #pragma unroll
        for (int r = 0; r < 4; ++r) {
            const int dc = c0 + quad * 4 + r;
            float v = acc[r] + bv[dc];
            vtile[(sub * 256 + (dc - cb)) * 32 + sh + n] = f16bits(v);
        }
    }
    __syncthreads();

    #pragma unroll
    for (int k = 0; k < 8; ++k) {
        const int slot = k * 256 + tid;
        const int li   = slot & 3;
        const int cl   = (slot >> 2) & 255;
        const int sb   = slot >> 10;
        const int c    = cb + cl;
        uint4 vv = *(const uint4*)(vtile + (sb * 256 + cl) * 32 + li * 8);
        *(uint4*)(vws + ((size_t)(b * 8 + (c >> 6)) * 64 + (c & 63)) * S_
                      + s0 + sb * 32 + li * 8) = vv;
    }
}

// ---------------------------------------------------------------------------
// Kernel 2: flash attention, 32 q/wave (4 waves/SIMD) WITH pipelining:
//   - K register-double-buffered (prefetched one full iter ahead)
//   - V issued at iter top, consumed ~300cyc later (post QK+exp half 0)
//   - exp->pack->PV split in two k-halves: PV(half0) overlaps exp(half1)
// Register peak ~122 (32 AGPR o + 16 qb + 32 kf + 16 va + transients) <= 128.
// grid (S/128, BH) = 1024 blocks = 4 blocks/CU. Output FLOAT32.
// ---------------------------------------------------------------------------
#define OST 68   // epilogue LDS row stride (f32)

__global__ __launch_bounds__(256, 4)
void flash_kernel(const short* __restrict__ qws, const short* __restrict__ kws,
                  const short* __restrict__ vws, float* __restrict__ out)
{
    __shared__ __align__(16) float olds[4 * 32 * OST];   // 34.8 KB

    const int tid  = threadIdx.x;
    const int wave = tid >> 6;
    const int lane = tid & 63;
    const int m32  = lane & 31;
    const int lh   = lane >> 5;          // lane-half
    const int koff = lh * 8;
    const bool lh0 = (lh == 0);
    const int bh   = blockIdx.y;
    const int q0   = blockIdx.x * 128 + wave * 32;

    const short* qbase = qws + (size_t)bh * S_ * D_;
    const short* kbase = kws + (size_t)bh * S_ * D_;
    const short* vbase = vws + (size_t)bh * D_ * S_;

    // Q^T B-frags (held): qb[h]: B[d=h*16+lh*8+j][q=m32]
    f16x8 qb[4];
    #pragma unroll
    for (int h = 0; h < 4; ++h)
        qb[h] = *(const f16x8*)(qbase + (q0 + m32) * D_ + h * 16 + koff);

    f32x16 o[2];        // [d-tile] O^T accumulators
    float  pl = 0.f;    // per-lane row-sum partial
    #pragma unroll
    for (int t = 0; t < 2; ++t)
        #pragma unroll
        for (int r = 0; r < 16; ++r) o[t][r] = 0.f;

    // K prefetch (double-buffered in regs)
    f16x8 kf[2][4];
    #pragma unroll
    for (int h = 0; h < 4; ++h)
        kf[0][h] = *(const f16x8*)(kbase + (size_t)m32 * D_ + h * 16 + koff);

    #pragma unroll 2
    for (int it = 0; it < 64; ++it) {
        const int cur = it & 1, nx = cur ^ 1;
        const int kt  = it << 5;
        const int nkt = ((it + 1) & 63) << 5;   // wrap: harmless re-read

        // V loads for THIS iter — consumed after QK+exp(half0), ~300cyc away
        f16x8 va[4];
        #pragma unroll
        for (int t = 0; t < 2; ++t)
            #pragma unroll
            for (int kh = 0; kh < 2; ++kh)
                va[t * 2 + kh] = *(const f16x8*)(vbase + (size_t)(t * 32 + m32) * S_ + kt + kh * 16 + koff);

        // QK with prefetched K (no load wait on critical path)
        f32x16 st;
        #pragma unroll
        for (int r = 0; r < 16; ++r) st[r] = 0.f;
        #pragma unroll
        for (int h = 0; h < 4; ++h)
            st = __builtin_amdgcn_mfma_f32_32x32x16_f16(kf[cur][h], qb[h], st, 0, 0, 0);

        // prefetch K for next iter (consumed next iter: full-iter distance)
        #pragma unroll
        for (int h = 0; h < 4; ++h)
            kf[nx][h] = *(const f16x8*)(kbase + (size_t)(nkt + m32) * D_ + h * 16 + koff);

        // ---- half 0: st[0..7] (k-half kh=0) -> bf0 -> 2 PV mfma ----
        {
            float p[8];
            #pragma unroll
            for (int r = 0; r < 8; ++r) p[r] = __expf(st[r]);
            pl += ((p[0]+p[1]) + (p[2]+p[3])) + ((p[4]+p[5]) + (p[6]+p[7]));
            unsigned int pk[4], xk[4];
            #pragma unroll
            for (int i = 0; i < 4; ++i)
                pk[i] = __builtin_bit_cast(unsigned int,
                          __builtin_amdgcn_cvt_pkrtz(p[2*i], p[2*i+1]));
            #pragma unroll
            for (int i = 0; i < 4; ++i)
                xk[i] = (unsigned int)__shfl_xor((int)pk[i], 32);
            i32x4 bi;
            bi[0] = (int)(lh0 ? pk[0] : xk[2]);
            bi[1] = (int)(lh0 ? pk[1] : xk[3]);
            bi[2] = (int)(lh0 ? xk[0] : pk[2]);
            bi[3] = (int)(lh0 ? xk[1] : pk[3]);
            f16x8 bf0 = __builtin_bit_cast(f16x8, bi);
            o[0] = __builtin_amdgcn_mfma_f32_32x32x16_f16(va[0], bf0, o[0], 0, 0, 0);
            o[1] = __builtin_amdgcn_mfma_f32_32x32x16_f16(va[2], bf0, o[1], 0, 0, 0);
        }
        // ---- half 1: st[8..15] (k-half kh=1) -> bf1 -> 2 PV mfma ----
        {
            float p[8];
            #pragma unroll
            for (int r = 0; r < 8; ++r) p[r] = __expf(st[8 + r]);
            pl += ((p[0]+p[1]) + (p[2]+p[3])) + ((p[4]+p[5]) + (p[6]+p[7]));
            unsigned int pk[4], xk[4];
            #pragma unroll
            for (int i = 0; i < 4; ++i)
                pk[i] = __builtin_bit_cast(unsigned int,
                          __builtin_amdgcn_cvt_pkrtz(p[2*i], p[2*i+1]));
            #pragma unroll
            for (int i = 0; i < 4; ++i)
                xk[i] = (unsigned int)__shfl_xor((int)pk[i], 32);
            i32x4 bi;
            bi[0] = (int)(lh0 ? pk[0] : xk[2]);
            bi[1] = (int)(lh0 ? pk[1] : xk[3]);
            bi[2] = (int)(lh0 ? xk[0] : pk[2]);
            bi[3] = (int)(lh0 ? xk[1] : pk[3]);
            f16x8 bf1 = __builtin_bit_cast(f16x8, bi);
            o[0] = __builtin_amdgcn_mfma_f32_32x32x16_f16(va[1], bf1, o[0], 0, 0, 0);
            o[1] = __builtin_amdgcn_mfma_f32_32x32x16_f16(va[3], bf1, o[1], 0, 0, 0);
        }
    }

    // epilogue: complete row sums across lane-halves, normalize,
    // transpose O^T -> O through per-wave LDS, coalesced f32x4 stores.
    const int b = bh >> 3, h = bh & 7;
    float* ow = olds + wave * (32 * OST);
    float rs = pl + __shfl_xor(pl, 32);
    float rl = 1.0f / rs;
    #pragma unroll
    for (int t = 0; t < 2; ++t)
        #pragma unroll
        for (int g = 0; g < 4; ++g) {
            f32x4 w;
            w[0] = o[t][g * 4 + 0] * rl;
            w[1] = o[t][g * 4 + 1] * rl;
            w[2] = o[t][g * 4 + 2] * rl;
            w[3] = o[t][g * 4 + 3] * rl;
            *(f32x4*)(ow + m32 * OST + t * 32 + 8 * g + 4 * lh) = w;
        }
    #pragma unroll
    for (int c = 0; c < 8; ++c) {
        const int row = c * 4 + (lane >> 4);
        f32x4 v = *(const f32x4*)(ow + row * OST + (lane & 15) * 4);
        const int sq = q0 + row;
        *(f32x4*)(out + ((size_t)(b * S_ + sq)) * DPROJ_ + h * 64 + (lane & 15) * 4) = v;
    }
}

// ---------------------------------------------------------------------------
extern "C" void kernel_launch(void* const* d_in, const int* in_sizes, int n_in,
                              void* d_out, int out_size, void* d_ws, size_t ws_size,
                              hipStream_t stream)
{
    const float* query = (const float*)d_in[0];
    const float* key   = (const float*)d_in[1];
    const float* value = (const float*)d_in[2];
    // d_in[3] = mask (int32) -- only its shape feeds the reference; unused.
    const float* Wq = (const float*)d_in[4];
    const float* bq = (const float*)d_in[5];
    const float* Wk = (const float*)d_in[6];
    const float* bk = (const float*)d_in[7];
    const float* Wv = (const float*)d_in[8];
    const float* bv = (const float*)d_in[9];

    float* out = (float*)d_out;
    short* ws  = (short*)d_ws;
    const size_t TSZ = (size_t)BH_ * S_ * D_;
    short* qws = ws;
    short* kws = ws + TSZ;
    short* vws = ws + 2 * TSZ;

    proj_qk_kernel<<<dim3((B_ * S_) / 16, 2), 256, 0, stream>>>(
        query, key, Wq, bq, Wk, bk, qws, kws);
    proj_v_kernel<<<dim3((B_ * S_) / 64, 2), 256, 0, stream>>>(
        value, Wv, bv, vws);
    flash_kernel<<<dim3(S_ / 128, BH_), 256, 0, stream>>>(qws, kws, vws, out);
}

// Round 10
// 199.786 us; speedup vs baseline: 1.7779x; 1.7779x over previous
//
#include <hip/hip_runtime.h>
#include <hip/hip_bf16.h>
#include <math.h>

// Problem constants
#define B_   8
#define H_   8
#define S_   2048
#define D_   64      // head dim
#define BH_  64      // B*H
#define DPROJ_ 512

typedef __attribute__((ext_vector_type(8)))  _Float16 f16x8;
typedef __attribute__((ext_vector_type(4)))  float    f32x4;
typedef __attribute__((ext_vector_type(16))) float    f32x16;
typedef __attribute__((ext_vector_type(4)))  int      i32x4;

static __device__ __forceinline__ short f16bits(float f) {
    return __builtin_bit_cast(short, (_Float16)f);   // v_cvt_f16_f32 (RNE)
}

static __device__ __forceinline__ f16x8 load8_f32_f16(const float* p) {
    const float4 a = ((const float4*)p)[0];
    const float4 b = ((const float4*)p)[1];
    f16x8 r;
    r[0] = (_Float16)a.x; r[1] = (_Float16)a.y; r[2] = (_Float16)a.z; r[3] = (_Float16)a.w;
    r[4] = (_Float16)b.x; r[5] = (_Float16)b.y; r[6] = (_Float16)b.z; r[7] = (_Float16)b.w;
    return r;
}

// ---------------------------------------------------------------------------
// Kernel 1a: Q/K projection (unchanged — passes, minor cost).
//   q_ws,k_ws: [BH][S][64] f16. q pre-scaled by 0.1125 (=0.9/8).
// ---------------------------------------------------------------------------
#define QKST 520

__global__ __launch_bounds__(256)
void proj_qk_kernel(const float* __restrict__ query, const float* __restrict__ key,
                    const float* __restrict__ Wq, const float* __restrict__ bq,
                    const float* __restrict__ Wk, const float* __restrict__ bk,
                    short* __restrict__ qws, short* __restrict__ kws)
{
    __shared__ __align__(16) short tile[16 * QKST];

    const int tid  = threadIdx.x;
    const int wave = tid >> 6;
    const int lane = tid & 63;
    const int n    = lane & 15;
    const int quad = lane >> 4;
    const int r0   = blockIdx.x * 16;
    const int kind = blockIdx.y;             // 0=q, 1=k
    const int b    = r0 >> 11;
    const int s0   = r0 & 2047;
    const float QS = 0.1125f;                // (1-dropout)/num_heads = 0.9/8

    const float* X    = kind ? key : query;
    const float* W    = kind ? Wk  : Wq;
    const float* bias = kind ? bk  : bq;
    short*       ows  = kind ? kws : qws;

    f16x8 af = load8_f32_f16(X + (r0 + n) * 32 + quad * 8);
    #pragma unroll
    for (int i = 0; i < 8; ++i) {
        const int c0 = wave * 128 + i * 16;
        f16x8 bfr = load8_f32_f16(W + (c0 + n) * 32 + quad * 8);
        f32x4 acc = {0.f, 0.f, 0.f, 0.f};
        acc = __builtin_amdgcn_mfma_f32_16x16x32_f16(af, bfr, acc, 0, 0, 0);
        const int c = c0 + n;
        const float bsf = bias[c];
        #pragma unroll
        for (int r = 0; r < 4; ++r) {
            float v = acc[r] + bsf;
            if (kind == 0) v *= QS;
            tile[(quad * 4 + r) * QKST + c] = f16bits(v);
        }
    }
    __syncthreads();

    #pragma unroll
    for (int k = 0; k < 4; ++k) {
        const int slot = k * 256 + tid;
        const int li   = slot & 7;
        const int chunk= slot >> 3;
        const int row  = chunk & 15;
        const int h    = chunk >> 4;
        uint4 vv = *(const uint4*)(tile + row * QKST + h * 64 + li * 8);
        *(uint4*)(ows + ((size_t)(b * 8 + h) * S_ + s0 + row) * 64 + li * 8) = vv;
    }
}

// ---------------------------------------------------------------------------
// Kernel 1b: V projection. NEW blocked output layout:
//   v_ws[bh][s_tile][d][ks]  (s_tile = s/32, ks = s%32)  f16
// so each 32-k V^T tile is a contiguous 4 KB chunk for flash LDS staging.
// ---------------------------------------------------------------------------
__global__ __launch_bounds__(256)
void proj_v_kernel(const float* __restrict__ value,
                   const float* __restrict__ Wv, const float* __restrict__ bv,
                   short* __restrict__ vws)
{
    __shared__ __align__(16) short vtile[2 * 256 * 32];   // 32 KB

    const int tid  = threadIdx.x;
    const int wave = tid >> 6;
    const int lane = tid & 63;
    const int n    = lane & 15;
    const int quad = lane >> 4;
    const int r0   = blockIdx.x * 64;
    const int cb   = blockIdx.y * 256;
    const int b    = r0 >> 11;
    const int s0   = r0 & 2047;
    const int sub  = wave >> 1;
    const int sh   = (wave & 1) * 16;

    f16x8 bfr = load8_f32_f16(value + (r0 + sub * 32 + sh + n) * 32 + quad * 8);
    #pragma unroll
    for (int i = 0; i < 16; ++i) {
        const int c0 = cb + i * 16;
        f16x8 af = load8_f32_f16(Wv + (c0 + n) * 32 + quad * 8);
        f32x4 acc = {0.f, 0.f, 0.f, 0.f};
        acc = __builtin_amdgcn_mfma_f32_16x16x32_f16(af, bfr, acc, 0, 0, 0);
        #pragma unroll
        for (int r = 0; r < 4; ++r) {
            const int dc = c0 + quad * 4 + r;
            float v = acc[r] + bv[dc];
            vtile[(sub * 256 + (dc - cb)) * 32 + sh + n] = f16bits(v);
        }
    }
    __syncthreads();

    // write out: blocked layout, 1KB-contiguous per 16-d group, coalesced
    #pragma unroll
    for (int k = 0; k < 8; ++k) {
        const int slot = k * 256 + tid;
        const int li   = slot & 3;
        const int cl   = (slot >> 2) & 255;
        const int sb   = slot >> 10;
        const int c    = cb + cl;
        const int bh   = b * 8 + (c >> 6);
        const int d    = c & 63;
        const int stile= (s0 >> 5) + sb;
        uint4 vv = *(const uint4*)(vtile + (sb * 256 + cl) * 32 + li * 8);
        *(uint4*)(vws + (((size_t)bh * (S_ / 32) + stile) * 64 + d) * 32 + li * 8) = vv;
    }
}

// ---------------------------------------------------------------------------
// Kernel 2: flash attention, R6 compute body + BLOCK-LEVEL LDS STAGING.
// Root fix: fragment loads from global were 32-cacheline gathers (4x L1
// transaction amplification) -> all waves queued on L1. Now: per 32-k tile,
// the 256-thread block stages K (4KB) and V (4KB) with ONE fully-coalesced
// 16B/thread load each, double-buffered in LDS; waves read fragments via
// ds_read_b128 (padded rows: K=72, V=40 shorts -> bank-balanced, 16B-aligned).
// 4 waves share each tile (4x traffic cut). 2-barrier m97-style loop.
// grid (S/256, BH) = 512 blocks. Output FLOAT32.
// ---------------------------------------------------------------------------
#define KST 72   // K lds row stride (shorts): 144B, 16B-aligned
#define VST 40   // V lds row stride (shorts): 80B, 16B-aligned
#define OST 68   // epilogue LDS row stride (f32)

__global__ __launch_bounds__(256, 2)
void flash_kernel(const short* __restrict__ qws, const short* __restrict__ kws,
                  const short* __restrict__ vws, float* __restrict__ out)
{
    __shared__ __align__(16) short ldsk[2 * 32 * KST];   //  9.2 KB
    __shared__ __align__(16) short ldsv[2 * 64 * VST];   // 10.2 KB
    __shared__ __align__(16) float olds[4 * 32 * OST];   // 34.8 KB

    const int tid  = threadIdx.x;
    const int wave = tid >> 6;
    const int lane = tid & 63;
    const int m32  = lane & 31;
    const int lh   = lane >> 5;          // lane-half
    const int koff = lh * 8;
    const bool lh0 = (lh == 0);
    const int bh   = blockIdx.y;
    const int q0   = blockIdx.x * 256 + wave * 64;

    const short* qbase = qws + (size_t)bh * S_ * D_;
    const short* kbase = kws + (size_t)bh * S_ * D_;
    const short* vbase = vws + (size_t)bh * (S_ / 32) * 2048;  // blocked tiles

    // staging addresses (per thread, fixed)
    const int krow = tid >> 3, kcol = (tid & 7) * 8;   // K: 8 thr/row of 64
    const int vrow = tid >> 2, vcol = (tid & 3) * 8;   // V: 4 thr/row of 32
    short* kdst0 = ldsk + krow * KST + kcol;
    short* vdst0 = ldsv + vrow * VST + vcol;

    // Q^T B-frags (held): qb[qg][h]: B[d=h*16+lh*8+j][q=m32]
    f16x8 qb[2][4];
    #pragma unroll
    for (int qg = 0; qg < 2; ++qg)
        #pragma unroll
        for (int h = 0; h < 4; ++h)
            qb[qg][h] = *(const f16x8*)(qbase + (q0 + qg * 32 + m32) * D_ + h * 16 + koff);

    f32x16 o[2][2];      // [qg][d-tile] O^T accumulators
    float  pl[2] = {0.f, 0.f};
    #pragma unroll
    for (int qg = 0; qg < 2; ++qg)
        #pragma unroll
        for (int t = 0; t < 2; ++t)
            #pragma unroll
            for (int r = 0; r < 16; ++r) o[qg][t][r] = 0.f;

    // stage tile 0 into buffer 0
    {
        uint4 kr = *(const uint4*)(kbase + (size_t)tid * 8);
        uint4 vr = *(const uint4*)(vbase + (size_t)tid * 8);
        *(uint4*)kdst0 = kr;
        *(uint4*)vdst0 = vr;
    }
    __syncthreads();

    for (int it = 0; it < 64; ++it) {
        const int cur = it & 1, nx = cur ^ 1;

        // issue next-tile global loads early (coalesced 16B/thread, 4KB each)
        uint4 kr, vr;
        if (it < 63) {
            kr = *(const uint4*)(kbase + (size_t)(it + 1) * 2048 + tid * 8);
            vr = *(const uint4*)(vbase + (size_t)(it + 1) * 2048 + tid * 8);
        }

        // ---- compute on buffer cur ----
        const short* kl = ldsk + cur * (32 * KST);
        const short* vl = ldsv + cur * (64 * VST);
        f16x8 kf[4], va[4];
        #pragma unroll
        for (int h = 0; h < 4; ++h)
            kf[h] = *(const f16x8*)(kl + m32 * KST + h * 16 + koff);
        #pragma unroll
        for (int t = 0; t < 2; ++t)
            #pragma unroll
            for (int kh = 0; kh < 2; ++kh)
                va[t * 2 + kh] = *(const f16x8*)(vl + (t * 32 + m32) * VST + kh * 16 + koff);

        #pragma unroll
        for (int qg = 0; qg < 2; ++qg) {
            f32x16 st;
            #pragma unroll
            for (int r = 0; r < 16; ++r) st[r] = 0.f;
            #pragma unroll
            for (int h = 0; h < 4; ++h)
                st = __builtin_amdgcn_mfma_f32_32x32x16_f16(kf[h], qb[qg][h], st, 0, 0, 0);

            float p[16];
            #pragma unroll
            for (int r = 0; r < 16; ++r) p[r] = __expf(st[r]);
            float s01 = (p[0]+p[1]) + (p[2]+p[3]);
            float s23 = (p[4]+p[5]) + (p[6]+p[7]);
            float s45 = (p[8]+p[9]) + (p[10]+p[11]);
            float s67 = (p[12]+p[13]) + (p[14]+p[15]);
            pl[qg] += (s01 + s23) + (s45 + s67);

            unsigned int pk[8], xk[8];
            #pragma unroll
            for (int i = 0; i < 8; ++i)
                pk[i] = __builtin_bit_cast(unsigned int,
                          __builtin_amdgcn_cvt_pkrtz(p[2 * i], p[2 * i + 1]));
            #pragma unroll
            for (int i = 0; i < 8; ++i)
                xk[i] = (unsigned int)__shfl_xor((int)pk[i], 32);

            i32x4 bi0, bi1;
            bi0[0] = (int)(lh0 ? pk[0] : xk[2]);
            bi0[1] = (int)(lh0 ? pk[1] : xk[3]);
            bi0[2] = (int)(lh0 ? xk[0] : pk[2]);
            bi0[3] = (int)(lh0 ? xk[1] : pk[3]);
            bi1[0] = (int)(lh0 ? pk[4] : xk[6]);
            bi1[1] = (int)(lh0 ? pk[5] : xk[7]);
            bi1[2] = (int)(lh0 ? xk[4] : pk[6]);
            bi1[3] = (int)(lh0 ? xk[5] : pk[7]);
            f16x8 bf0 = __builtin_bit_cast(f16x8, bi0);
            f16x8 bf1 = __builtin_bit_cast(f16x8, bi1);

            #pragma unroll
            for (int t = 0; t < 2; ++t) {
                o[qg][t] = __builtin_amdgcn_mfma_f32_32x32x16_f16(va[t * 2 + 0], bf0, o[qg][t], 0, 0, 0);
                o[qg][t] = __builtin_amdgcn_mfma_f32_32x32x16_f16(va[t * 2 + 1], bf1, o[qg][t], 0, 0, 0);
            }
        }

        __syncthreads();   // all waves done reading buffer cur
        if (it < 63) {
            *(uint4*)(kdst0 + nx * (32 * KST)) = kr;
            *(uint4*)(vdst0 + nx * (64 * VST)) = vr;
        }
        __syncthreads();   // staging visible before next iter's reads
    }

    // epilogue: complete row sums across lane-halves, normalize,
    // transpose O^T -> O through per-wave LDS, coalesced f32x4 stores.
    const int b = bh >> 3, h = bh & 7;
    float* ow = olds + wave * (32 * OST);
    #pragma unroll
    for (int qg = 0; qg < 2; ++qg) {
        float rs = pl[qg] + __shfl_xor(pl[qg], 32);
        float rl = 1.0f / rs;
        #pragma unroll
        for (int t = 0; t < 2; ++t)
            #pragma unroll
            for (int g = 0; g < 4; ++g) {
                f32x4 w;
                w[0] = o[qg][t][g * 4 + 0] * rl;
                w[1] = o[qg][t][g * 4 + 1] * rl;
                w[2] = o[qg][t][g * 4 + 2] * rl;
                w[3] = o[qg][t][g * 4 + 3] * rl;
                *(f32x4*)(ow + m32 * OST + t * 32 + 8 * g + 4 * lh) = w;
            }
        #pragma unroll
        for (int c = 0; c < 8; ++c) {
            const int row = c * 4 + (lane >> 4);
            f32x4 v = *(const f32x4*)(ow + row * OST + (lane & 15) * 4);
            const int sq = q0 + qg * 32 + row;
            *(f32x4*)(out + ((size_t)(b * S_ + sq)) * DPROJ_ + h * 64 + (lane & 15) * 4) = v;
        }
    }
}

// ---------------------------------------------------------------------------
extern "C" void kernel_launch(void* const* d_in, const int* in_sizes, int n_in,
                              void* d_out, int out_size, void* d_ws, size_t ws_size,
                              hipStream_t stream)
{
    const float* query = (const float*)d_in[0];
    const float* key   = (const float*)d_in[1];
    const float* value = (const float*)d_in[2];
    // d_in[3] = mask (int32) -- only its shape feeds the reference; unused.
    const float* Wq = (const float*)d_in[4];
    const float* bq = (const float*)d_in[5];
    const float* Wk = (const float*)d_in[6];
    const float* bk = (const float*)d_in[7];
    const float* Wv = (const float*)d_in[8];
    const float* bv = (const float*)d_in[9];

    float* out = (float*)d_out;
    short* ws  = (short*)d_ws;
    const size_t TSZ = (size_t)BH_ * S_ * D_;
    short* qws = ws;
    short* kws = ws + TSZ;
    short* vws = ws + 2 * TSZ;

    proj_qk_kernel<<<dim3((B_ * S_) / 16, 2), 256, 0, stream>>>(
        query, key, Wq, bq, Wk, bk, qws, kws);
    proj_v_kernel<<<dim3((B_ * S_) / 64, 2), 256, 0, stream>>>(
        value, Wv, bv, vws);
    flash_kernel<<<dim3(S_ / 256, BH_), 256, 0, stream>>>(qws, kws, vws, out);
}